// Round 6
// baseline (349.736 us; speedup 1.0000x reference)
//
#include <hip/hip_runtime.h>

#define HID 64
#define FEAT 10
#define STAGE_CAP 6144   // csr_build LDS staging entries (max bucket ~4400)

// ---------- helpers ----------
__device__ inline unsigned short f2bf(float f) {          // fp32 -> bf16 RNE
    unsigned u = __float_as_uint(f);
    unsigned r = (u + 0x7fffu + ((u >> 16) & 1u)) >> 16;
    return (unsigned short)r;
}
// decode 8 bf16 (uint4) and fma into acc[8] with weight w
__device__ inline void bf8_fma(float* acc, uint4 u, float w) {
    acc[0] += __uint_as_float(u.x << 16) * w;
    acc[1] += __uint_as_float(u.x & 0xffff0000u) * w;
    acc[2] += __uint_as_float(u.y << 16) * w;
    acc[3] += __uint_as_float(u.y & 0xffff0000u) * w;
    acc[4] += __uint_as_float(u.z << 16) * w;
    acc[5] += __uint_as_float(u.z & 0xffff0000u) * w;
    acc[6] += __uint_as_float(u.w << 16) * w;
    acc[7] += __uint_as_float(u.w & 0xffff0000u) * w;
}
// csr entry: u32 = (src << 16) | bf16_bits(weight)
__device__ inline int csr_src(unsigned e) { return (int)(e >> 16); }
__device__ inline float csr_w(unsigned e) { return __uint_as_float(e << 16); }

// ================= CSR build (bucketed, coalesced) =================

// per-node histogram (global atomics) + per-chunk bucket histogram (LDS).
// chunk = 4096 edges, block = 1024 threads (4 edges/thread). bucket = dst>>8.
__global__ void histA(const int* __restrict__ dst, int* __restrict__ cnt,
                      int* __restrict__ cnt2, int E, int nbuckets) {
    __shared__ int lh[256];
    int t = threadIdx.x, c = blockIdx.x;
    if (t < 256) lh[t] = 0;
    __syncthreads();
    int base = c * 4096;
    #pragma unroll
    for (int j = 0; j < 4; j++) {
        int e = base + t + j * 1024;
        if (e < E) {
            int d = dst[e];
            atomicAdd(&cnt[d], 1);
            atomicAdd(&lh[d >> 8], 1);
        }
    }
    __syncthreads();
    if (t < nbuckets) cnt2[c * nbuckets + t] = lh[t];
}

__global__ void bsum_kernel(const int* __restrict__ cnt, int* __restrict__ bsum, int N) {
    __shared__ int lds[256];
    int i = blockIdx.x * 256 + threadIdx.x;
    lds[threadIdx.x] = (i < N) ? cnt[i] : 0;
    __syncthreads();
    for (int off = 128; off > 0; off >>= 1) {
        if (threadIdx.x < off) lds[threadIdx.x] += lds[threadIdx.x + off];
        __syncthreads();
    }
    if (threadIdx.x == 0) bsum[blockIdx.x] = lds[0];
}

__global__ void bscan_kernel(int* __restrict__ bsum, int* __restrict__ row_ptr, int nb, int N) {
    __shared__ int lds[256];
    int t = threadIdx.x;
    int v = (t < nb) ? bsum[t] : 0;
    lds[t] = v;
    __syncthreads();
    for (int off = 1; off < 256; off <<= 1) {
        int a = lds[t];
        int b = (t >= off) ? lds[t - off] : 0;
        __syncthreads();
        lds[t] = a + b;
        __syncthreads();
    }
    if (t < nb) bsum[t] = lds[t] - v;
    if (t == 0) row_ptr[N] = lds[255];
}

// chunk scan + dinv (fused). cursor no longer needed.
__global__ void chunk_scan_kernel(const int* __restrict__ cnt, const int* __restrict__ bsum,
                                  int* __restrict__ row_ptr, float* __restrict__ dinv, int N) {
    __shared__ int lds[256];
    int t = threadIdx.x;
    int i = blockIdx.x * 256 + t;
    int v = (i < N) ? cnt[i] : 0;
    lds[t] = v;
    __syncthreads();
    for (int off = 1; off < 256; off <<= 1) {
        int a = lds[t];
        int b = (t >= off) ? lds[t - off] : 0;
        __syncthreads();
        lds[t] = a + b;
        __syncthreads();
    }
    if (i < N) {
        row_ptr[i] = bsum[blockIdx.x] + lds[t] - v;
        dinv[i]    = rsqrtf((float)v + 1.0f);
    }
}

// off2[chunk][bucket] = row_ptr[bucket*256] + prefix over chunks of cnt2[.][bucket]
// single block; threads = buckets (coalesced loads across threads).
__global__ void off2_kernel(const int* __restrict__ cnt2, const int* __restrict__ row_ptr,
                            int* __restrict__ off2, int nchunks, int nbuckets) {
    int b = threadIdx.x;
    if (b >= nbuckets) return;
    int run = row_ptr[b * 256];
    for (int c = 0; c < nchunks; c++) {
        off2[c * nbuckets + b] = run;
        run += cnt2[c * nbuckets + b];
    }
}

// bin edges by bucket into contiguous per-(bucket,chunk) runs of tmp (coalesced-ish writes).
// tmp entry: {dst, packed(src,wbf16)}
__global__ void binpass(const int* __restrict__ src, const int* __restrict__ dst,
                        const float* __restrict__ dinv, const int* __restrict__ off2,
                        int2* __restrict__ tmp, int E, int nbuckets) {
    __shared__ int cur[256];
    int t = threadIdx.x, c = blockIdx.x;
    if (t < 256) cur[t] = (t < nbuckets) ? off2[c * nbuckets + t] : 0;
    __syncthreads();
    int base = c * 4096;
    #pragma unroll
    for (int j = 0; j < 4; j++) {
        int e = base + t + j * 1024;
        if (e < E) {
            int s = src[e], d = dst[e];
            float w = dinv[s] * dinv[d];
            int slot = atomicAdd(&cur[d >> 8], 1);
            unsigned packed = ((unsigned)s << 16) | (unsigned)f2bf(w);
            tmp[slot] = make_int2(d, (int)packed);
        }
    }
}

// one block per bucket: bin by exact dst into LDS staging, stream out coalesced.
__global__ void csr_build(const int2* __restrict__ tmp, const int* __restrict__ row_ptr,
                          unsigned* __restrict__ csr, int N) {
    __shared__ unsigned staged[STAGE_CAP];
    __shared__ int curL[256];
    int b = blockIdx.x, t = threadIdx.x;
    int node0 = b * 256;
    int nodeEnd = min(node0 + 256, N);
    int segBase = row_ptr[node0];
    int segEnd  = row_ptr[nodeEnd];   // row_ptr[N] == E
    if (t < 256) {
        int n = node0 + t;
        curL[t] = (n < nodeEnd) ? (row_ptr[n] - segBase) : 0;
    }
    __syncthreads();
    int segLen = segEnd - segBase;
    for (int i = t; i < segLen; i += 1024) {
        int2 en = tmp[segBase + i];
        int local = en.x - node0;
        int idx = atomicAdd(&curL[local], 1);
        if (idx < STAGE_CAP) staged[idx] = (unsigned)en.y;
        else csr[segBase + idx] = (unsigned)en.y;   // safety fallback (not expected)
    }
    __syncthreads();
    for (int i = t; i < segLen && i < STAGE_CAP; i += 1024)
        csr[segBase + i] = staged[i];
}

// ================= layer 1: pad x, aggregate raw x, then matmul =================

__global__ void pad_x(const float* __restrict__ x, float* __restrict__ xp, int N) {
    int idx = blockIdx.x * 256 + threadIdx.x;
    if (idx >= N * 16) return;
    int n = idx >> 4, c = idx & 15;
    xp[idx] = (c < FEAT) ? x[n * FEAT + c] : 0.0f;
}

// aggx[n][16] = wself*xp[n] + sum_e w_e * xp[src_e]; 4 lanes/node, float4 per lane.
__global__ void gather_x(const int* __restrict__ row_ptr, const unsigned* __restrict__ csr,
                         const float* __restrict__ xp, const float* __restrict__ dinv,
                         float* __restrict__ aggx, int N) {
    int t = threadIdx.x;
    int node = blockIdx.x * 64 + (t >> 2);
    if (node >= N) return;
    int c0 = (t & 3) * 4;
    float di = dinv[node];
    float ws = di * di;
    float4 sv = *(const float4*)(xp + (size_t)node * 16 + c0);
    float4 acc = make_float4(sv.x * ws, sv.y * ws, sv.z * ws, sv.w * ws);
    int i = row_ptr[node], i1 = row_ptr[node + 1];
    for (; i + 8 <= i1; i += 8) {
        unsigned e0 = csr[i], e1 = csr[i+1], e2 = csr[i+2], e3 = csr[i+3];
        unsigned e4 = csr[i+4], e5 = csr[i+5], e6 = csr[i+6], e7 = csr[i+7];
        float4 u0 = *(const float4*)(xp + (size_t)csr_src(e0) * 16 + c0);
        float4 u1 = *(const float4*)(xp + (size_t)csr_src(e1) * 16 + c0);
        float4 u2 = *(const float4*)(xp + (size_t)csr_src(e2) * 16 + c0);
        float4 u3 = *(const float4*)(xp + (size_t)csr_src(e3) * 16 + c0);
        float4 u4 = *(const float4*)(xp + (size_t)csr_src(e4) * 16 + c0);
        float4 u5 = *(const float4*)(xp + (size_t)csr_src(e5) * 16 + c0);
        float4 u6 = *(const float4*)(xp + (size_t)csr_src(e6) * 16 + c0);
        float4 u7 = *(const float4*)(xp + (size_t)csr_src(e7) * 16 + c0);
        float w0 = csr_w(e0), w1 = csr_w(e1), w2 = csr_w(e2), w3 = csr_w(e3);
        float w4 = csr_w(e4), w5 = csr_w(e5), w6 = csr_w(e6), w7 = csr_w(e7);
        acc.x += u0.x*w0 + u1.x*w1 + u2.x*w2 + u3.x*w3 + u4.x*w4 + u5.x*w5 + u6.x*w6 + u7.x*w7;
        acc.y += u0.y*w0 + u1.y*w1 + u2.y*w2 + u3.y*w3 + u4.y*w4 + u5.y*w5 + u6.y*w6 + u7.y*w7;
        acc.z += u0.z*w0 + u1.z*w1 + u2.z*w2 + u3.z*w3 + u4.z*w4 + u5.z*w5 + u6.z*w6 + u7.z*w7;
        acc.w += u0.w*w0 + u1.w*w1 + u2.w*w2 + u3.w*w3 + u4.w*w4 + u5.w*w5 + u6.w*w6 + u7.w*w7;
    }
    for (; i < i1; i++) {
        unsigned e0 = csr[i];
        float w0 = csr_w(e0);
        float4 u0 = *(const float4*)(xp + (size_t)csr_src(e0) * 16 + c0);
        acc.x += u0.x*w0; acc.y += u0.y*w0; acc.z += u0.z*w0; acc.w += u0.w*w0;
    }
    *(float4*)(aggx + (size_t)node * 16 + c0) = acc;
}

// h1 = relu(aggx @ W1 + b1), fp32. 64 nodes/block, 4 nodes x 4 cols per thread.
__global__ void gcn_matmul1(const float* __restrict__ aggx, const float* __restrict__ W1,
                            const float* __restrict__ b1, float* __restrict__ h1, int N) {
    __shared__ float sW[FEAT * 64];
    __shared__ float sH[64 * 16];
    int t = threadIdx.x;
    int node0 = blockIdx.x * 64;
    for (int i = t; i < FEAT * 64; i += 256) sW[i] = W1[i];
    for (int i = t; i < 64 * 16; i += 256) {
        int r = i >> 4, k = i & 15;
        int node = node0 + r;
        sH[i] = (node < N) ? aggx[(size_t)node * 16 + k] : 0.0f;
    }
    __syncthreads();
    int c0 = (t & 15) * 4;
    int rbase = (t >> 4) * 4;
    float4 a0 = {0,0,0,0}, a1 = {0,0,0,0}, a2 = {0,0,0,0}, a3 = {0,0,0,0};
    for (int k = 0; k < FEAT; k++) {
        float4 w = *(const float4*)(sW + k * 64 + c0);
        float h0 = sH[(rbase + 0) * 16 + k];
        float h1v = sH[(rbase + 1) * 16 + k];
        float h2 = sH[(rbase + 2) * 16 + k];
        float h3 = sH[(rbase + 3) * 16 + k];
        a0.x += h0 * w.x; a0.y += h0 * w.y; a0.z += h0 * w.z; a0.w += h0 * w.w;
        a1.x += h1v * w.x; a1.y += h1v * w.y; a1.z += h1v * w.z; a1.w += h1v * w.w;
        a2.x += h2 * w.x; a2.y += h2 * w.y; a2.z += h2 * w.z; a2.w += h2 * w.w;
        a3.x += h3 * w.x; a3.y += h3 * w.y; a3.z += h3 * w.z; a3.w += h3 * w.w;
    }
    float4 bb = *(const float4*)(b1 + c0);
    float4 accs[4] = {a0, a1, a2, a3};
    for (int rr = 0; rr < 4; rr++) {
        int node = node0 + rbase + rr;
        if (node >= N) break;
        float4 v = accs[rr];
        v.x = fmaxf(v.x + bb.x, 0.f); v.y = fmaxf(v.y + bb.y, 0.f);
        v.z = fmaxf(v.z + bb.z, 0.f); v.w = fmaxf(v.w + bb.w, 0.f);
        *(float4*)(h1 + (size_t)node * 64 + c0) = v;
    }
}

// ================= layers 2/3 =================

// hwb (half-split) = bf16(h_in @ W): hwb[half][node][32]. 64 nodes/block.
__global__ void gcn_matmul64(const float* __restrict__ h_in, const float* __restrict__ W,
                             unsigned short* __restrict__ hwb, int N) {
    __shared__ float sW[64 * 64];
    __shared__ float sH[64 * 65];
    int t = threadIdx.x;
    int node0 = blockIdx.x * 64;
    for (int i = t * 4; i < 4096; i += 1024)
        *(float4*)(sW + i) = *(const float4*)(W + i);
    for (int i = t; i < 4096; i += 256) {
        int r = i >> 6, k = i & 63;
        int node = node0 + r;
        sH[r * 65 + k] = (node < N) ? h_in[(size_t)node * 64 + k] : 0.0f;
    }
    __syncthreads();
    int c0 = (t & 15) * 4;
    int rbase = (t >> 4) * 4;
    float4 a0 = {0,0,0,0}, a1 = {0,0,0,0}, a2 = {0,0,0,0}, a3 = {0,0,0,0};
    for (int k = 0; k < 64; k++) {
        float4 w = *(const float4*)(sW + k * 64 + c0);
        float h0 = sH[(rbase + 0) * 65 + k];
        float h1v = sH[(rbase + 1) * 65 + k];
        float h2 = sH[(rbase + 2) * 65 + k];
        float h3 = sH[(rbase + 3) * 65 + k];
        a0.x += h0 * w.x; a0.y += h0 * w.y; a0.z += h0 * w.z; a0.w += h0 * w.w;
        a1.x += h1v * w.x; a1.y += h1v * w.y; a1.z += h1v * w.z; a1.w += h1v * w.w;
        a2.x += h2 * w.x; a2.y += h2 * w.y; a2.z += h2 * w.z; a2.w += h2 * w.w;
        a3.x += h3 * w.x; a3.y += h3 * w.y; a3.z += h3 * w.z; a3.w += h3 * w.w;
    }
    int half = c0 >> 5;
    int cin  = c0 & 31;
    float4 accs[4] = {a0, a1, a2, a3};
    for (int rr = 0; rr < 4; rr++) {
        int node = node0 + rbase + rr;
        if (node >= N) break;
        float4 v = accs[rr];
        ushort4 o;
        o.x = f2bf(v.x); o.y = f2bf(v.y); o.z = f2bf(v.z); o.w = f2bf(v.w);
        *(ushort4*)(hwb + ((size_t)half * N + node) * 32 + cin) = o;
    }
}

// column-split gather: half = 32 cols (3.2 MB working set, L2-resident per XCD).
__global__ void gather_bf(const int* __restrict__ row_ptr, const unsigned* __restrict__ csr,
                          const unsigned short* __restrict__ hwb,
                          const float* __restrict__ dinv, const float* __restrict__ b,
                          float* __restrict__ out, float* __restrict__ gsum,
                          int N, int halfGrid, int do_gsum) {
    int t = threadIdx.x;
    int half = (blockIdx.x >= halfGrid) ? 1 : 0;
    int node = (blockIdx.x - half * halfGrid) * 64 + (t >> 2);
    int q = t & 3;
    int c0 = q * 8;
    const unsigned short* hb = hwb + (size_t)half * N * 32;
    float acc[8] = {0.f,0.f,0.f,0.f,0.f,0.f,0.f,0.f};
    if (node < N) {
        float di = dinv[node];
        uint4 sv = *(const uint4*)(hb + (size_t)node * 32 + c0);
        bf8_fma(acc, sv, di * di);
        int i = row_ptr[node], i1 = row_ptr[node + 1];
        for (; i + 8 <= i1; i += 8) {
            unsigned e0 = csr[i], e1 = csr[i+1], e2 = csr[i+2], e3 = csr[i+3];
            unsigned e4 = csr[i+4], e5 = csr[i+5], e6 = csr[i+6], e7 = csr[i+7];
            uint4 u0 = *(const uint4*)(hb + (size_t)csr_src(e0) * 32 + c0);
            uint4 u1 = *(const uint4*)(hb + (size_t)csr_src(e1) * 32 + c0);
            uint4 u2 = *(const uint4*)(hb + (size_t)csr_src(e2) * 32 + c0);
            uint4 u3 = *(const uint4*)(hb + (size_t)csr_src(e3) * 32 + c0);
            uint4 u4 = *(const uint4*)(hb + (size_t)csr_src(e4) * 32 + c0);
            uint4 u5 = *(const uint4*)(hb + (size_t)csr_src(e5) * 32 + c0);
            uint4 u6 = *(const uint4*)(hb + (size_t)csr_src(e6) * 32 + c0);
            uint4 u7 = *(const uint4*)(hb + (size_t)csr_src(e7) * 32 + c0);
            bf8_fma(acc, u0, csr_w(e0));
            bf8_fma(acc, u1, csr_w(e1));
            bf8_fma(acc, u2, csr_w(e2));
            bf8_fma(acc, u3, csr_w(e3));
            bf8_fma(acc, u4, csr_w(e4));
            bf8_fma(acc, u5, csr_w(e5));
            bf8_fma(acc, u6, csr_w(e6));
            bf8_fma(acc, u7, csr_w(e7));
        }
        for (; i < i1; i++) {
            unsigned e0 = csr[i];
            uint4 u0 = *(const uint4*)(hb + (size_t)csr_src(e0) * 32 + c0);
            bf8_fma(acc, u0, csr_w(e0));
        }
        float4 o0, o1;
        int cg = half * 32 + c0;
        const float4 bb0 = *(const float4*)(b + cg);
        const float4 bb1 = *(const float4*)(b + cg + 4);
        o0.x = fmaxf(acc[0] + bb0.x, 0.f); o0.y = fmaxf(acc[1] + bb0.y, 0.f);
        o0.z = fmaxf(acc[2] + bb0.z, 0.f); o0.w = fmaxf(acc[3] + bb0.w, 0.f);
        o1.x = fmaxf(acc[4] + bb1.x, 0.f); o1.y = fmaxf(acc[5] + bb1.y, 0.f);
        o1.z = fmaxf(acc[6] + bb1.z, 0.f); o1.w = fmaxf(acc[7] + bb1.w, 0.f);
        *(float4*)(out + (size_t)node * 64 + cg)     = o0;
        *(float4*)(out + (size_t)node * 64 + cg + 4) = o1;
        acc[0]=o0.x; acc[1]=o0.y; acc[2]=o0.z; acc[3]=o0.w;
        acc[4]=o1.x; acc[5]=o1.y; acc[6]=o1.z; acc[7]=o1.w;
    } else {
        for (int j = 0; j < 8; j++) acc[j] = 0.f;
    }
    if (do_gsum) {
        __shared__ float red[64 * 32];
        int nl = t >> 2;
        for (int j = 0; j < 8; j++) red[nl * 32 + c0 + j] = acc[j];
        __syncthreads();
        if (t < 32) {
            float s = 0.f;
            #pragma unroll
            for (int k = 0; k < 64; k++) s += red[k * 32 + t];
            atomicAdd(&gsum[half * 32 + t], s);
        }
    }
}

// ================= head =================

__global__ void final_kernel(const float* __restrict__ h3, const int* __restrict__ sheet_idx,
                             const float* __restrict__ sheet_feat, const float* __restrict__ g_sum,
                             const float* __restrict__ gW1, const float* __restrict__ gb1,
                             const float* __restrict__ gW2, const float* __restrict__ gb2,
                             const float* __restrict__ fW,  const float* __restrict__ fb,
                             const float* __restrict__ qW1, const float* __restrict__ qb1,
                             const float* __restrict__ qW2, const float* __restrict__ qb2,
                             float* __restrict__ out, int N, int L) {
    int s = blockIdx.x, t = threadIdx.x;
    __shared__ float red[256];
    __shared__ float semb[64];
    __shared__ float geoh[64];
    __shared__ float geo[64];
    __shared__ float hq[128];
    int c = t & 63, jg = t >> 6;
    float acc = 0.0f;
    for (int j = jg; j < L; j += 4) {
        int node = sheet_idx[s * L + j];
        acc += h3[(size_t)node * 64 + c];
    }
    red[t] = acc;
    __syncthreads();
    if (t < 64) {
        semb[t] = (red[t] + red[t + 64] + red[t + 128] + red[t + 192]) / (float)L;
        hq[64 + t] = g_sum[t] / (float)N;
        float a = gb1[t];
        #pragma unroll
        for (int k = 0; k < FEAT; k++) a += sheet_feat[s * FEAT + k] * gW1[k * 64 + t];
        geoh[t] = fmaxf(a, 0.0f);
    }
    __syncthreads();
    if (t < 64) {
        float a = gb2[t];
        for (int k = 0; k < 64; k++) a += geoh[k] * gW2[k * 64 + t];
        geo[t] = a;
    }
    __syncthreads();
    if (t < 64) {
        float a = fb[t];
        for (int k = 0; k < 64; k++) a += semb[k] * fW[k * 64 + t];
        for (int k = 0; k < 64; k++) a += geo[k]  * fW[(64 + k) * 64 + t];
        hq[t] = fmaxf(a, 0.0f);
    }
    __syncthreads();
    float q = 0.0f;
    if (t < 64) {
        float a = qb1[t];
        for (int k = 0; k < 128; k++) a += hq[k] * qW1[k * 64 + t];
        a = fmaxf(a, 0.0f);
        q = a * qW2[t];
        for (int off = 32; off > 0; off >>= 1) q += __shfl_down(q, off, 64);
        if (t == 0) out[s] = q + qb2[0];
    }
}

extern "C" void kernel_launch(void* const* d_in, const int* in_sizes, int n_in,
                              void* d_out, int out_size, void* d_ws, size_t ws_size,
                              hipStream_t stream) {
    const float* x          = (const float*)d_in[0];
    const int*   edge       = (const int*)d_in[1];
    const int*   sheet_idx  = (const int*)d_in[3];
    const float* sheet_feat = (const float*)d_in[4];
    const float* W1 = (const float*)d_in[5];  const float* b1 = (const float*)d_in[6];
    const float* W2 = (const float*)d_in[7];  const float* b2 = (const float*)d_in[8];
    const float* W3 = (const float*)d_in[9];  const float* b3 = (const float*)d_in[10];
    const float* gW1 = (const float*)d_in[11]; const float* gb1 = (const float*)d_in[12];
    const float* gW2 = (const float*)d_in[13]; const float* gb2 = (const float*)d_in[14];
    const float* fW  = (const float*)d_in[15]; const float* fb  = (const float*)d_in[16];
    const float* qW1 = (const float*)d_in[17]; const float* qb1 = (const float*)d_in[18];
    const float* qW2 = (const float*)d_in[19]; const float* qb2 = (const float*)d_in[20];
    float* out = (float*)d_out;

    int N = in_sizes[2];            // 50000
    int E = in_sizes[1] / 2;        // 800000
    int S = in_sizes[4] / FEAT;     // 256
    int L = in_sizes[3] / S;        // 128

    int nb       = (N + 255) / 256;     // 196 scan blocks (<=256 required)
    int nbuckets = (N + 255) / 256;     // 196 (requires N <= 65536 for u16 src)
    int nchunks  = (E + 4095) / 4096;   // 196

    // ---- workspace layout (16B-aligned big blocks first) ----
    char* p = (char*)d_ws;
    int2*  tmp     = (int2*)p;                 p += (size_t)E * 8;              // 6.4 MB
    unsigned* csr  = (unsigned*)p;             p += (size_t)E * 4;              // 3.2 MB
    float* hf      = (float*)p;                p += (size_t)N * 64 * 4;         // 12.8 MB
    unsigned short* hwb = (unsigned short*)p;  p += (size_t)N * 64 * 2;         // 6.4 MB
    float* xp      = (float*)p;                p += (size_t)N * 16 * 4;         // 3.2 MB
    float* aggx    = (float*)p;                p += (size_t)N * 16 * 4;         // 3.2 MB
    int*   cnt     = (int*)p;                  p += (size_t)N * 4;
    int*   row_ptr = (int*)p;                  p += (size_t)(N + 1) * 4;
    int*   bsum    = (int*)p;                  p += 256 * 4;
    float* dinv    = (float*)p;                p += (size_t)N * 4;
    float* gsum    = (float*)p;                p += 64 * 4;
    int*   cnt2    = (int*)p;                  p += (size_t)nchunks * nbuckets * 4;
    int*   off2    = (int*)p;                  /* nchunks*nbuckets*4 */

    hipMemsetAsync(cnt, 0, (size_t)N * 4, stream);
    hipMemsetAsync(gsum, 0, 64 * 4, stream);

    const int* src = edge;
    const int* dst = edge + E;

    int gMM = (N + 63) / 64;
    int halfGrid = (N + 63) / 64;
    int gGB = 2 * halfGrid;
    int gPX = (N * 16 + 255) / 256;

    // CSR build (bucketed, coalesced writes)
    histA<<<nchunks, 1024, 0, stream>>>(dst, cnt, cnt2, E, nbuckets);
    bsum_kernel<<<nb, 256, 0, stream>>>(cnt, bsum, N);
    bscan_kernel<<<1, 256, 0, stream>>>(bsum, row_ptr, nb, N);
    chunk_scan_kernel<<<nb, 256, 0, stream>>>(cnt, bsum, row_ptr, dinv, N);
    off2_kernel<<<1, 256, 0, stream>>>(cnt2, row_ptr, off2, nchunks, nbuckets);
    binpass<<<nchunks, 1024, 0, stream>>>(src, dst, dinv, off2, tmp, E, nbuckets);
    csr_build<<<nbuckets, 1024, 0, stream>>>(tmp, row_ptr, csr, N);

    // layer 1 (linear trick): pad x, aggregate, matmul -> hf (h1)
    pad_x<<<gPX, 256, 0, stream>>>(x, xp, N);
    gather_x<<<halfGrid, 256, 0, stream>>>(row_ptr, csr, xp, dinv, aggx, N);
    gcn_matmul1<<<gMM, 256, 0, stream>>>(aggx, W1, b1, hf, N);

    // layer 2: hf @ W2 -> hwb (bf16, half-split); gather -> hf (h2)
    gcn_matmul64<<<gMM, 256, 0, stream>>>(hf, W2, hwb, N);
    gather_bf<<<gGB, 256, 0, stream>>>(row_ptr, csr, hwb, dinv, b2, hf, gsum, N, halfGrid, 0);

    // layer 3: hf @ W3 -> hwb; gather -> hf (h3) + gsum
    gcn_matmul64<<<gMM, 256, 0, stream>>>(hf, W3, hwb, N);
    gather_bf<<<gGB, 256, 0, stream>>>(row_ptr, csr, hwb, dinv, b3, hf, gsum, N, halfGrid, 1);

    final_kernel<<<S, 256, 0, stream>>>(hf, sheet_idx, sheet_feat, gsum,
                                        gW1, gb1, gW2, gb2, fW, fb,
                                        qW1, qb1, qW2, qb2, out, N, L);
}

// Round 7
// 306.851 us; speedup vs baseline: 1.1398x; 1.1398x over previous
//
#include <hip/hip_runtime.h>

#define HID 64
#define FEAT 10
#define STAGE_CAP 6144   // csr_build LDS staging entries (max bucket ~4400)

// ---------- helpers ----------
__device__ inline unsigned short f2bf(float f) {          // fp32 -> bf16 RNE
    unsigned u = __float_as_uint(f);
    unsigned r = (u + 0x7fffu + ((u >> 16) & 1u)) >> 16;
    return (unsigned short)r;
}
// decode 8 bf16 (uint4) and fma into acc[8] with weight w
__device__ inline void bf8_fma(float* acc, uint4 u, float w) {
    acc[0] += __uint_as_float(u.x << 16) * w;
    acc[1] += __uint_as_float(u.x & 0xffff0000u) * w;
    acc[2] += __uint_as_float(u.y << 16) * w;
    acc[3] += __uint_as_float(u.y & 0xffff0000u) * w;
    acc[4] += __uint_as_float(u.z << 16) * w;
    acc[5] += __uint_as_float(u.z & 0xffff0000u) * w;
    acc[6] += __uint_as_float(u.w << 16) * w;
    acc[7] += __uint_as_float(u.w & 0xffff0000u) * w;
}
// csr entry: u32 = (src << 16) | bf16_bits(weight)
__device__ inline int csr_src(unsigned e) { return (int)(e >> 16); }
__device__ inline float csr_w(unsigned e) { return __uint_as_float(e << 16); }

// ================= CSR build (bucketed, coalesced) =================

// per-node histogram (global atomics) + per-chunk bucket histogram (LDS).
// chunk = 4096 edges, block = 1024 threads. cnt2T layout: [bucket][chunk].
__global__ void histA(const int* __restrict__ dst, int* __restrict__ cnt,
                      int* __restrict__ cnt2T, int E, int nbuckets, int nchunks) {
    __shared__ int lh[256];
    int t = threadIdx.x, c = blockIdx.x;
    if (t < 256) lh[t] = 0;
    __syncthreads();
    int base = c * 4096;
    #pragma unroll
    for (int j = 0; j < 4; j++) {
        int e = base + t + j * 1024;
        if (e < E) {
            int d = dst[e];
            atomicAdd(&cnt[d], 1);
            atomicAdd(&lh[d >> 8], 1);
        }
    }
    __syncthreads();
    if (t < nbuckets) cnt2T[t * nchunks + c] = lh[t];
}

__global__ void bsum_kernel(const int* __restrict__ cnt, int* __restrict__ bsum, int N) {
    __shared__ int lds[256];
    int i = blockIdx.x * 256 + threadIdx.x;
    lds[threadIdx.x] = (i < N) ? cnt[i] : 0;
    __syncthreads();
    for (int off = 128; off > 0; off >>= 1) {
        if (threadIdx.x < off) lds[threadIdx.x] += lds[threadIdx.x + off];
        __syncthreads();
    }
    if (threadIdx.x == 0) bsum[blockIdx.x] = lds[0];
}

__global__ void bscan_kernel(int* __restrict__ bsum, int* __restrict__ row_ptr, int nb, int N) {
    __shared__ int lds[256];
    int t = threadIdx.x;
    int v = (t < nb) ? bsum[t] : 0;
    lds[t] = v;
    __syncthreads();
    for (int off = 1; off < 256; off <<= 1) {
        int a = lds[t];
        int b = (t >= off) ? lds[t - off] : 0;
        __syncthreads();
        lds[t] = a + b;
        __syncthreads();
    }
    if (t < nb) bsum[t] = lds[t] - v;
    if (t == 0) row_ptr[N] = lds[255];
}

// chunk scan + dinv (fused)
__global__ void chunk_scan_kernel(const int* __restrict__ cnt, const int* __restrict__ bsum,
                                  int* __restrict__ row_ptr, float* __restrict__ dinv, int N) {
    __shared__ int lds[256];
    int t = threadIdx.x;
    int i = blockIdx.x * 256 + t;
    int v = (i < N) ? cnt[i] : 0;
    lds[t] = v;
    __syncthreads();
    for (int off = 1; off < 256; off <<= 1) {
        int a = lds[t];
        int b = (t >= off) ? lds[t - off] : 0;
        __syncthreads();
        lds[t] = a + b;
        __syncthreads();
    }
    if (i < N) {
        row_ptr[i] = bsum[blockIdx.x] + lds[t] - v;
        dinv[i]    = rsqrtf((float)v + 1.0f);
    }
}

// parallel per-bucket exclusive scan over chunks: one block per bucket.
// off2T[b][c] = row_ptr[b*256] + sum_{c'<c} cnt2T[b][c']
__global__ void off2_scan(const int* __restrict__ cnt2T, const int* __restrict__ row_ptr,
                          int* __restrict__ off2T, int nchunks) {
    __shared__ int lds[256];
    int b = blockIdx.x, t = threadIdx.x;
    int v = (t < nchunks) ? cnt2T[b * nchunks + t] : 0;
    lds[t] = v;
    __syncthreads();
    for (int off = 1; off < 256; off <<= 1) {
        int a = lds[t];
        int s = (t >= off) ? lds[t - off] : 0;
        __syncthreads();
        lds[t] = a + s;
        __syncthreads();
    }
    if (t < nchunks) off2T[b * nchunks + t] = row_ptr[b * 256] + lds[t] - v;
}

// bin edges by bucket into contiguous per-(bucket,chunk) runs of tmp.
// tmp entry: {dst, packed(src,wbf16)}
__global__ void binpass(const int* __restrict__ src, const int* __restrict__ dst,
                        const float* __restrict__ dinv, const int* __restrict__ off2T,
                        int2* __restrict__ tmp, int E, int nbuckets, int nchunks) {
    __shared__ int cur[256];
    int t = threadIdx.x, c = blockIdx.x;
    if (t < 256) cur[t] = (t < nbuckets) ? off2T[t * nchunks + c] : 0;
    __syncthreads();
    int base = c * 4096;
    #pragma unroll
    for (int j = 0; j < 4; j++) {
        int e = base + t + j * 1024;
        if (e < E) {
            int s = src[e], d = dst[e];
            float w = dinv[s] * dinv[d];
            int slot = atomicAdd(&cur[d >> 8], 1);
            unsigned packed = ((unsigned)s << 16) | (unsigned)f2bf(w);
            tmp[slot] = make_int2(d, (int)packed);
        }
    }
}

// one block per bucket: bin by exact dst into LDS staging, stream out coalesced.
__global__ void csr_build(const int2* __restrict__ tmp, const int* __restrict__ row_ptr,
                          unsigned* __restrict__ csr, int N) {
    __shared__ unsigned staged[STAGE_CAP];
    __shared__ int curL[256];
    int b = blockIdx.x, t = threadIdx.x;
    int node0 = b * 256;
    int nodeEnd = min(node0 + 256, N);
    int segBase = row_ptr[node0];
    int segEnd  = row_ptr[nodeEnd];   // row_ptr[N] == E
    if (t < 256) {
        int n = node0 + t;
        curL[t] = (n < nodeEnd) ? (row_ptr[n] - segBase) : 0;
    }
    __syncthreads();
    int segLen = segEnd - segBase;
    for (int i = t; i < segLen; i += 1024) {
        int2 en = tmp[segBase + i];
        int local = en.x - node0;
        int idx = atomicAdd(&curL[local], 1);
        if (idx < STAGE_CAP) staged[idx] = (unsigned)en.y;
        else csr[segBase + idx] = (unsigned)en.y;   // safety fallback (not expected)
    }
    __syncthreads();
    for (int i = t; i < segLen && i < STAGE_CAP; i += 1024)
        csr[segBase + i] = staged[i];
}

// ================= layer 1: pad x, aggregate raw x, then matmul =================

__global__ void pad_x(const float* __restrict__ x, float* __restrict__ xp, int N) {
    int idx = blockIdx.x * 256 + threadIdx.x;
    if (idx >= N * 16) return;
    int n = idx >> 4, c = idx & 15;
    xp[idx] = (c < FEAT) ? x[n * FEAT + c] : 0.0f;
}

// aggx[n][16] = wself*xp[n] + sum_e w_e * xp[src_e]; 4 lanes/node, float4 per lane.
__global__ void gather_x(const int* __restrict__ row_ptr, const unsigned* __restrict__ csr,
                         const float* __restrict__ xp, const float* __restrict__ dinv,
                         float* __restrict__ aggx, int N) {
    int t = threadIdx.x;
    int node = blockIdx.x * 64 + (t >> 2);
    if (node >= N) return;
    int c0 = (t & 3) * 4;
    float di = dinv[node];
    float ws = di * di;
    float4 sv = *(const float4*)(xp + (size_t)node * 16 + c0);
    float4 acc = make_float4(sv.x * ws, sv.y * ws, sv.z * ws, sv.w * ws);
    int i = row_ptr[node], i1 = row_ptr[node + 1];
    for (; i + 8 <= i1; i += 8) {
        unsigned e0 = csr[i], e1 = csr[i+1], e2 = csr[i+2], e3 = csr[i+3];
        unsigned e4 = csr[i+4], e5 = csr[i+5], e6 = csr[i+6], e7 = csr[i+7];
        float4 u0 = *(const float4*)(xp + (size_t)csr_src(e0) * 16 + c0);
        float4 u1 = *(const float4*)(xp + (size_t)csr_src(e1) * 16 + c0);
        float4 u2 = *(const float4*)(xp + (size_t)csr_src(e2) * 16 + c0);
        float4 u3 = *(const float4*)(xp + (size_t)csr_src(e3) * 16 + c0);
        float4 u4 = *(const float4*)(xp + (size_t)csr_src(e4) * 16 + c0);
        float4 u5 = *(const float4*)(xp + (size_t)csr_src(e5) * 16 + c0);
        float4 u6 = *(const float4*)(xp + (size_t)csr_src(e6) * 16 + c0);
        float4 u7 = *(const float4*)(xp + (size_t)csr_src(e7) * 16 + c0);
        float w0 = csr_w(e0), w1 = csr_w(e1), w2 = csr_w(e2), w3 = csr_w(e3);
        float w4 = csr_w(e4), w5 = csr_w(e5), w6 = csr_w(e6), w7 = csr_w(e7);
        acc.x += u0.x*w0 + u1.x*w1 + u2.x*w2 + u3.x*w3 + u4.x*w4 + u5.x*w5 + u6.x*w6 + u7.x*w7;
        acc.y += u0.y*w0 + u1.y*w1 + u2.y*w2 + u3.y*w3 + u4.y*w4 + u5.y*w5 + u6.y*w6 + u7.y*w7;
        acc.z += u0.z*w0 + u1.z*w1 + u2.z*w2 + u3.z*w3 + u4.z*w4 + u5.z*w5 + u6.z*w6 + u7.z*w7;
        acc.w += u0.w*w0 + u1.w*w1 + u2.w*w2 + u3.w*w3 + u4.w*w4 + u5.w*w5 + u6.w*w6 + u7.w*w7;
    }
    for (; i < i1; i++) {
        unsigned e0 = csr[i];
        float w0 = csr_w(e0);
        float4 u0 = *(const float4*)(xp + (size_t)csr_src(e0) * 16 + c0);
        acc.x += u0.x*w0; acc.y += u0.y*w0; acc.z += u0.z*w0; acc.w += u0.w*w0;
    }
    *(float4*)(aggx + (size_t)node * 16 + c0) = acc;
}

// h1 = relu(aggx @ W1 + b1), fp32. 64 nodes/block, 4 nodes x 4 cols per thread.
__global__ void gcn_matmul1(const float* __restrict__ aggx, const float* __restrict__ W1,
                            const float* __restrict__ b1, float* __restrict__ h1, int N) {
    __shared__ float sW[FEAT * 64];
    __shared__ float sH[64 * 16];
    int t = threadIdx.x;
    int node0 = blockIdx.x * 64;
    for (int i = t; i < FEAT * 64; i += 256) sW[i] = W1[i];
    for (int i = t; i < 64 * 16; i += 256) {
        int r = i >> 4, k = i & 15;
        int node = node0 + r;
        sH[i] = (node < N) ? aggx[(size_t)node * 16 + k] : 0.0f;
    }
    __syncthreads();
    int c0 = (t & 15) * 4;
    int rbase = (t >> 4) * 4;
    float4 a0 = {0,0,0,0}, a1 = {0,0,0,0}, a2 = {0,0,0,0}, a3 = {0,0,0,0};
    for (int k = 0; k < FEAT; k++) {
        float4 w = *(const float4*)(sW + k * 64 + c0);
        float h0 = sH[(rbase + 0) * 16 + k];
        float h1v = sH[(rbase + 1) * 16 + k];
        float h2 = sH[(rbase + 2) * 16 + k];
        float h3 = sH[(rbase + 3) * 16 + k];
        a0.x += h0 * w.x; a0.y += h0 * w.y; a0.z += h0 * w.z; a0.w += h0 * w.w;
        a1.x += h1v * w.x; a1.y += h1v * w.y; a1.z += h1v * w.z; a1.w += h1v * w.w;
        a2.x += h2 * w.x; a2.y += h2 * w.y; a2.z += h2 * w.z; a2.w += h2 * w.w;
        a3.x += h3 * w.x; a3.y += h3 * w.y; a3.z += h3 * w.z; a3.w += h3 * w.w;
    }
    float4 bb = *(const float4*)(b1 + c0);
    float4 accs[4] = {a0, a1, a2, a3};
    for (int rr = 0; rr < 4; rr++) {
        int node = node0 + rbase + rr;
        if (node >= N) break;
        float4 v = accs[rr];
        v.x = fmaxf(v.x + bb.x, 0.f); v.y = fmaxf(v.y + bb.y, 0.f);
        v.z = fmaxf(v.z + bb.z, 0.f); v.w = fmaxf(v.w + bb.w, 0.f);
        *(float4*)(h1 + (size_t)node * 64 + c0) = v;
    }
}

// ================= layers 2/3 =================

// hwb (half-split) = bf16(h_in @ W): hwb[half][node][32]. 64 nodes/block.
__global__ void gcn_matmul64(const float* __restrict__ h_in, const float* __restrict__ W,
                             unsigned short* __restrict__ hwb, int N) {
    __shared__ float sW[64 * 64];
    __shared__ float sH[64 * 65];
    int t = threadIdx.x;
    int node0 = blockIdx.x * 64;
    for (int i = t * 4; i < 4096; i += 1024)
        *(float4*)(sW + i) = *(const float4*)(W + i);
    for (int i = t; i < 4096; i += 256) {
        int r = i >> 6, k = i & 63;
        int node = node0 + r;
        sH[r * 65 + k] = (node < N) ? h_in[(size_t)node * 64 + k] : 0.0f;
    }
    __syncthreads();
    int c0 = (t & 15) * 4;
    int rbase = (t >> 4) * 4;
    float4 a0 = {0,0,0,0}, a1 = {0,0,0,0}, a2 = {0,0,0,0}, a3 = {0,0,0,0};
    for (int k = 0; k < 64; k++) {
        float4 w = *(const float4*)(sW + k * 64 + c0);
        float h0 = sH[(rbase + 0) * 65 + k];
        float h1v = sH[(rbase + 1) * 65 + k];
        float h2 = sH[(rbase + 2) * 65 + k];
        float h3 = sH[(rbase + 3) * 65 + k];
        a0.x += h0 * w.x; a0.y += h0 * w.y; a0.z += h0 * w.z; a0.w += h0 * w.w;
        a1.x += h1v * w.x; a1.y += h1v * w.y; a1.z += h1v * w.z; a1.w += h1v * w.w;
        a2.x += h2 * w.x; a2.y += h2 * w.y; a2.z += h2 * w.z; a2.w += h2 * w.w;
        a3.x += h3 * w.x; a3.y += h3 * w.y; a3.z += h3 * w.z; a3.w += h3 * w.w;
    }
    int half = c0 >> 5;
    int cin  = c0 & 31;
    float4 accs[4] = {a0, a1, a2, a3};
    for (int rr = 0; rr < 4; rr++) {
        int node = node0 + rbase + rr;
        if (node >= N) break;
        float4 v = accs[rr];
        ushort4 o;
        o.x = f2bf(v.x); o.y = f2bf(v.y); o.z = f2bf(v.z); o.w = f2bf(v.w);
        *(ushort4*)(hwb + ((size_t)half * N + node) * 32 + cin) = o;
    }
}

// column-split gather: half = 32 cols (3.2 MB working set, L2-resident per XCD).
__global__ void gather_bf(const int* __restrict__ row_ptr, const unsigned* __restrict__ csr,
                          const unsigned short* __restrict__ hwb,
                          const float* __restrict__ dinv, const float* __restrict__ b,
                          float* __restrict__ out, float* __restrict__ gsum,
                          int N, int halfGrid, int do_gsum) {
    int t = threadIdx.x;
    int half = (blockIdx.x >= halfGrid) ? 1 : 0;
    int node = (blockIdx.x - half * halfGrid) * 64 + (t >> 2);
    int q = t & 3;
    int c0 = q * 8;
    const unsigned short* hb = hwb + (size_t)half * N * 32;
    float acc[8] = {0.f,0.f,0.f,0.f,0.f,0.f,0.f,0.f};
    if (node < N) {
        float di = dinv[node];
        uint4 sv = *(const uint4*)(hb + (size_t)node * 32 + c0);
        bf8_fma(acc, sv, di * di);
        int i = row_ptr[node], i1 = row_ptr[node + 1];
        for (; i + 8 <= i1; i += 8) {
            unsigned e0 = csr[i], e1 = csr[i+1], e2 = csr[i+2], e3 = csr[i+3];
            unsigned e4 = csr[i+4], e5 = csr[i+5], e6 = csr[i+6], e7 = csr[i+7];
            uint4 u0 = *(const uint4*)(hb + (size_t)csr_src(e0) * 32 + c0);
            uint4 u1 = *(const uint4*)(hb + (size_t)csr_src(e1) * 32 + c0);
            uint4 u2 = *(const uint4*)(hb + (size_t)csr_src(e2) * 32 + c0);
            uint4 u3 = *(const uint4*)(hb + (size_t)csr_src(e3) * 32 + c0);
            uint4 u4 = *(const uint4*)(hb + (size_t)csr_src(e4) * 32 + c0);
            uint4 u5 = *(const uint4*)(hb + (size_t)csr_src(e5) * 32 + c0);
            uint4 u6 = *(const uint4*)(hb + (size_t)csr_src(e6) * 32 + c0);
            uint4 u7 = *(const uint4*)(hb + (size_t)csr_src(e7) * 32 + c0);
            bf8_fma(acc, u0, csr_w(e0));
            bf8_fma(acc, u1, csr_w(e1));
            bf8_fma(acc, u2, csr_w(e2));
            bf8_fma(acc, u3, csr_w(e3));
            bf8_fma(acc, u4, csr_w(e4));
            bf8_fma(acc, u5, csr_w(e5));
            bf8_fma(acc, u6, csr_w(e6));
            bf8_fma(acc, u7, csr_w(e7));
        }
        for (; i < i1; i++) {
            unsigned e0 = csr[i];
            uint4 u0 = *(const uint4*)(hb + (size_t)csr_src(e0) * 32 + c0);
            bf8_fma(acc, u0, csr_w(e0));
        }
        float4 o0, o1;
        int cg = half * 32 + c0;
        const float4 bb0 = *(const float4*)(b + cg);
        const float4 bb1 = *(const float4*)(b + cg + 4);
        o0.x = fmaxf(acc[0] + bb0.x, 0.f); o0.y = fmaxf(acc[1] + bb0.y, 0.f);
        o0.z = fmaxf(acc[2] + bb0.z, 0.f); o0.w = fmaxf(acc[3] + bb0.w, 0.f);
        o1.x = fmaxf(acc[4] + bb1.x, 0.f); o1.y = fmaxf(acc[5] + bb1.y, 0.f);
        o1.z = fmaxf(acc[6] + bb1.z, 0.f); o1.w = fmaxf(acc[7] + bb1.w, 0.f);
        *(float4*)(out + (size_t)node * 64 + cg)     = o0;
        *(float4*)(out + (size_t)node * 64 + cg + 4) = o1;
        acc[0]=o0.x; acc[1]=o0.y; acc[2]=o0.z; acc[3]=o0.w;
        acc[4]=o1.x; acc[5]=o1.y; acc[6]=o1.z; acc[7]=o1.w;
    } else {
        for (int j = 0; j < 8; j++) acc[j] = 0.f;
    }
    if (do_gsum) {
        __shared__ float red[64 * 32];
        int nl = t >> 2;
        for (int j = 0; j < 8; j++) red[nl * 32 + c0 + j] = acc[j];
        __syncthreads();
        if (t < 32) {
            float s = 0.f;
            #pragma unroll
            for (int k = 0; k < 64; k++) s += red[k * 32 + t];
            atomicAdd(&gsum[half * 32 + t], s);
        }
    }
}

// ================= head =================

__global__ void final_kernel(const float* __restrict__ h3, const int* __restrict__ sheet_idx,
                             const float* __restrict__ sheet_feat, const float* __restrict__ g_sum,
                             const float* __restrict__ gW1, const float* __restrict__ gb1,
                             const float* __restrict__ gW2, const float* __restrict__ gb2,
                             const float* __restrict__ fW,  const float* __restrict__ fb,
                             const float* __restrict__ qW1, const float* __restrict__ qb1,
                             const float* __restrict__ qW2, const float* __restrict__ qb2,
                             float* __restrict__ out, int N, int L) {
    int s = blockIdx.x, t = threadIdx.x;
    __shared__ float red[256];
    __shared__ float semb[64];
    __shared__ float geoh[64];
    __shared__ float geo[64];
    __shared__ float hq[128];
    int c = t & 63, jg = t >> 6;
    float acc = 0.0f;
    for (int j = jg; j < L; j += 4) {
        int node = sheet_idx[s * L + j];
        acc += h3[(size_t)node * 64 + c];
    }
    red[t] = acc;
    __syncthreads();
    if (t < 64) {
        semb[t] = (red[t] + red[t + 64] + red[t + 128] + red[t + 192]) / (float)L;
        hq[64 + t] = g_sum[t] / (float)N;
        float a = gb1[t];
        #pragma unroll
        for (int k = 0; k < FEAT; k++) a += sheet_feat[s * FEAT + k] * gW1[k * 64 + t];
        geoh[t] = fmaxf(a, 0.0f);
    }
    __syncthreads();
    if (t < 64) {
        float a = gb2[t];
        for (int k = 0; k < 64; k++) a += geoh[k] * gW2[k * 64 + t];
        geo[t] = a;
    }
    __syncthreads();
    if (t < 64) {
        float a = fb[t];
        for (int k = 0; k < 64; k++) a += semb[k] * fW[k * 64 + t];
        for (int k = 0; k < 64; k++) a += geo[k]  * fW[(64 + k) * 64 + t];
        hq[t] = fmaxf(a, 0.0f);
    }
    __syncthreads();
    float q = 0.0f;
    if (t < 64) {
        float a = qb1[t];
        for (int k = 0; k < 128; k++) a += hq[k] * qW1[k * 64 + t];
        a = fmaxf(a, 0.0f);
        q = a * qW2[t];
        for (int off = 32; off > 0; off >>= 1) q += __shfl_down(q, off, 64);
        if (t == 0) out[s] = q + qb2[0];
    }
}

extern "C" void kernel_launch(void* const* d_in, const int* in_sizes, int n_in,
                              void* d_out, int out_size, void* d_ws, size_t ws_size,
                              hipStream_t stream) {
    const float* x          = (const float*)d_in[0];
    const int*   edge       = (const int*)d_in[1];
    const int*   sheet_idx  = (const int*)d_in[3];
    const float* sheet_feat = (const float*)d_in[4];
    const float* W1 = (const float*)d_in[5];  const float* b1 = (const float*)d_in[6];
    const float* W2 = (const float*)d_in[7];  const float* b2 = (const float*)d_in[8];
    const float* W3 = (const float*)d_in[9];  const float* b3 = (const float*)d_in[10];
    const float* gW1 = (const float*)d_in[11]; const float* gb1 = (const float*)d_in[12];
    const float* gW2 = (const float*)d_in[13]; const float* gb2 = (const float*)d_in[14];
    const float* fW  = (const float*)d_in[15]; const float* fb  = (const float*)d_in[16];
    const float* qW1 = (const float*)d_in[17]; const float* qb1 = (const float*)d_in[18];
    const float* qW2 = (const float*)d_in[19]; const float* qb2 = (const float*)d_in[20];
    float* out = (float*)d_out;

    int N = in_sizes[2];            // 50000
    int E = in_sizes[1] / 2;        // 800000
    int S = in_sizes[4] / FEAT;     // 256
    int L = in_sizes[3] / S;        // 128

    int nb       = (N + 255) / 256;     // 196 scan blocks (<=256 required)
    int nbuckets = (N + 255) / 256;     // 196 (requires N <= 65536 for u16 src)
    int nchunks  = (E + 4095) / 4096;   // 196 (<=256 required for off2_scan)

    // ---- workspace layout (16B-aligned big blocks first) ----
    char* p = (char*)d_ws;
    int2*  tmp     = (int2*)p;                 p += (size_t)E * 8;              // 6.4 MB
    unsigned* csr  = (unsigned*)p;             p += (size_t)E * 4;              // 3.2 MB
    float* hf      = (float*)p;                p += (size_t)N * 64 * 4;         // 12.8 MB
    unsigned short* hwb = (unsigned short*)p;  p += (size_t)N * 64 * 2;         // 6.4 MB
    float* xp      = (float*)p;                p += (size_t)N * 16 * 4;         // 3.2 MB
    float* aggx    = (float*)p;                p += (size_t)N * 16 * 4;         // 3.2 MB
    int*   cnt     = (int*)p;                  p += (size_t)N * 4;
    int*   row_ptr = (int*)p;                  p += (size_t)(N + 1) * 4;
    int*   bsum    = (int*)p;                  p += 256 * 4;
    float* dinv    = (float*)p;                p += (size_t)N * 4;
    float* gsum    = (float*)p;                p += 64 * 4;
    int*   cnt2T   = (int*)p;                  p += (size_t)nbuckets * nchunks * 4;
    int*   off2T   = (int*)p;                  /* nbuckets*nchunks*4 */

    hipMemsetAsync(cnt, 0, (size_t)N * 4, stream);
    hipMemsetAsync(gsum, 0, 64 * 4, stream);

    const int* src = edge;
    const int* dst = edge + E;

    int gMM = (N + 63) / 64;
    int halfGrid = (N + 63) / 64;
    int gGB = 2 * halfGrid;
    int gPX = (N * 16 + 255) / 256;

    // CSR build (bucketed, coalesced writes; parallel offset scan)
    histA<<<nchunks, 1024, 0, stream>>>(dst, cnt, cnt2T, E, nbuckets, nchunks);
    bsum_kernel<<<nb, 256, 0, stream>>>(cnt, bsum, N);
    bscan_kernel<<<1, 256, 0, stream>>>(bsum, row_ptr, nb, N);
    chunk_scan_kernel<<<nb, 256, 0, stream>>>(cnt, bsum, row_ptr, dinv, N);
    off2_scan<<<nbuckets, 256, 0, stream>>>(cnt2T, row_ptr, off2T, nchunks);
    binpass<<<nchunks, 1024, 0, stream>>>(src, dst, dinv, off2T, tmp, E, nbuckets, nchunks);
    csr_build<<<nbuckets, 1024, 0, stream>>>(tmp, row_ptr, csr, N);

    // layer 1 (linear trick): pad x, aggregate, matmul -> hf (h1)
    pad_x<<<gPX, 256, 0, stream>>>(x, xp, N);
    gather_x<<<halfGrid, 256, 0, stream>>>(row_ptr, csr, xp, dinv, aggx, N);
    gcn_matmul1<<<gMM, 256, 0, stream>>>(aggx, W1, b1, hf, N);

    // layer 2: hf @ W2 -> hwb (bf16, half-split); gather -> hf (h2)
    gcn_matmul64<<<gMM, 256, 0, stream>>>(hf, W2, hwb, N);
    gather_bf<<<gGB, 256, 0, stream>>>(row_ptr, csr, hwb, dinv, b2, hf, gsum, N, halfGrid, 0);

    // layer 3: hf @ W3 -> hwb; gather -> hf (h3) + gsum
    gcn_matmul64<<<gMM, 256, 0, stream>>>(hf, W3, hwb, N);
    gather_bf<<<gGB, 256, 0, stream>>>(row_ptr, csr, hwb, dinv, b3, hf, gsum, N, halfGrid, 1);

    final_kernel<<<S, 256, 0, stream>>>(hf, sheet_idx, sheet_feat, gsum,
                                        gW1, gb1, gW2, gb2, fW, fb,
                                        qW1, qb1, qW2, qb2, out, N, L);
}